// Round 7
// baseline (1740.067 us; speedup 1.0000x reference)
//
#include <hip/hip_runtime.h>
#include <stdint.h>

namespace {

constexpr int Bb = 8, S = 4096, D = 1024, BS = 32768;
constexpr float SCALE = 0.08838834764831845f;           // (D/NUM_HEADS)^-0.5
constexpr float FEPS  = 1.1920928955078125e-07f;        // float32 eps (2^-23)
constexpr int MAXF = 4096;                              // max rescued items

typedef unsigned short u16;
typedef __attribute__((ext_vector_type(8))) _Float16 f16x8;
typedef __attribute__((ext_vector_type(4))) float    f32x4;

__device__ __forceinline__ u16 f2h(float f) {
  _Float16 h = (_Float16)f;
  return __builtin_bit_cast(u16, h);
}
__device__ __forceinline__ float h2f(u16 u) {
  return (float)__builtin_bit_cast(_Float16, u);
}
__device__ __forceinline__ void gload_lds16(const void* g, void* l) {
  __builtin_amdgcn_global_load_lds((const __attribute__((address_space(1))) void*)g,
                                   (__attribute__((address_space(3))) void*)l, 16, 0, 0);
}
#define VMCNT(n) asm volatile("s_waitcnt vmcnt(" #n ")" ::: "memory")

// ---------------------------------------------------------------- prep_h
__global__ void prep_h(const float* __restrict__ hidden, const float* __restrict__ pos,
                       u16* __restrict__ Hf, int* __restrict__ fcnt) {
  if (blockIdx.x == 0 && threadIdx.x == 0) *fcnt = 0;
  const int r = blockIdx.x;
  const int t = threadIdx.x;
  const float4 hv = ((const float4*)(hidden + (size_t)r * D))[t];
  const float4 pv = ((const float4*)(pos + (size_t)(r & (S - 1)) * D))[t];
  float x0 = hv.x + pv.x, x1 = hv.y + pv.y, x2 = hv.z + pv.z, x3 = hv.w + pv.w;
  float ss = x0 * x0 + x1 * x1 + x2 * x2 + x3 * x3;
  #pragma unroll
  for (int m = 1; m < 64; m <<= 1) ss += __shfl_xor(ss, m, 64);
  __shared__ float red[4];
  if ((t & 63) == 0) red[t >> 6] = ss;
  __syncthreads();
  const float nrm = fmaxf(sqrtf(red[0] + red[1] + red[2] + red[3]), 1e-12f);
  ((ushort4*)(Hf + (size_t)r * D))[t] = make_ushort4(
      f2h(x0 / nrm), f2h(x1 / nrm), f2h(x2 / nrm), f2h(x3 / nrm));
}

// ---------------------------------------------------------------- gemm_G_part
__global__ void gemm_G_part(const float* __restrict__ Wq, const float* __restrict__ Wk,
                            float* __restrict__ Gpart) {
  __shared__ float Qs[32][64];
  __shared__ float Ks[32][64];
  const int t = threadIdx.x;
  const int i0 = blockIdx.x * 64, j0 = blockIdx.y * 64;
  const int kz = blockIdx.z * 256;
  const int tx = t & 15, ty = t >> 4;
  float acc[4][4] = {};
  for (int k0 = kz; k0 < kz + 256; k0 += 32) {
    #pragma unroll
    for (int q = 0; q < 2; ++q) {
      const int c = t + q * 256;
      const int row = c >> 4, c4 = (c & 15) << 2;
      *(float4*)&Qs[row][c4] = *(const float4*)&Wq[(size_t)(k0 + row) * D + i0 + c4];
      *(float4*)&Ks[row][c4] = *(const float4*)&Wk[(size_t)(k0 + row) * D + j0 + c4];
    }
    __syncthreads();
    #pragma unroll 8
    for (int kk = 0; kk < 32; ++kk) {
      const float4 qa = *(const float4*)&Qs[kk][tx << 2];
      const float4 kb = *(const float4*)&Ks[kk][ty << 2];
      const float qq[4] = {qa.x, qa.y, qa.z, qa.w};
      const float kv[4] = {kb.x, kb.y, kb.z, kb.w};
      #pragma unroll
      for (int a = 0; a < 4; ++a)
        #pragma unroll
        for (int bj = 0; bj < 4; ++bj) acc[a][bj] = fmaf(qq[a], kv[bj], acc[a][bj]);
    }
    __syncthreads();
  }
  float* gp = Gpart + (size_t)blockIdx.z * 1048576;
  #pragma unroll
  for (int a = 0; a < 4; ++a) {
    const int i = i0 + (tx << 2) + a;
    *(float4*)&gp[(size_t)i * D + j0 + (ty << 2)] =
        make_float4(acc[a][0], acc[a][1], acc[a][2], acc[a][3]);
  }
}

// ---------------------------------------------------------------- gemm_G_comb
__global__ void gemm_G_comb(const float* __restrict__ Gpart,
                            float* __restrict__ Gf32, u16* __restrict__ Gf16) {
  const size_t e = ((size_t)blockIdx.x * 256 + threadIdx.x) * 4;
  float4 a = *(const float4*)&Gpart[e];
  #pragma unroll
  for (int z = 1; z < 4; ++z) {
    const float4 p = *(const float4*)&Gpart[(size_t)z * 1048576 + e];
    a.x += p.x; a.y += p.y; a.z += p.z; a.w += p.w;
  }
  *(float4*)&Gf32[e] = a;
  *(ushort4*)&Gf16[e] = make_ushort4(f2h(a.x), f2h(a.y), f2h(a.z), f2h(a.w));
}

// ---------------------------------------------------------------- gemm_main
// fp16 MFMA GEMM: A global->register (ping-pong, 1-tile prefetch, compiler
// vmcnt), B via LDS double-buffer (1 barrier + vmcnt(16)/tile). BM=BN=256
// BK=64, 8 waves (2 wr x 4 wc), per-wave 128x64. LDS 68KB -> 2 blocks/CU.
// A rows are wave-exclusive so reg-direct costs no extra HBM traffic; n-reuse
// of A is in-register, 8-wave reuse of B is through LDS (swizzled, 0-conflict).
// Fused epilogue: adj_part[nt][r] = sum_{i in tile} U[r,i]*Hf[r+1,i].
__global__ __launch_bounds__(512, 4) void gemm_main(
    const u16* __restrict__ Hf, const u16* __restrict__ Gf,
    float* __restrict__ adj_part) {
  __shared__ u16 Bbuf[2][16384];      // 2 x 32KB (256 rows x 64 k)
  __shared__ float adjp[4][256];

  const int tid = threadIdx.x;
  const int bid = blockIdx.x;
  const int swz = (bid & 7) * 64 + (bid >> 3);   // XCD swizzle (512 % 8 == 0)
  const int mt = swz >> 2, nt = swz & 3;
  const int r0 = mt << 8;
  const int n0g = nt << 8;

  const int wave = tid >> 6, lane = tid & 63;
  const int wr = wave >> 2;           // 0..1 -> rows wr*128
  const int wc = wave & 3;            // 0..3 -> cols wc*64
  const int frow = lane & 15;
  const int fgrp = lane >> 4;
  const int sw = (lane & 7) << 4;
  const int cb0 = (fgrp * 16) ^ sw;
  const int cb1 = (64 + fgrp * 16) ^ sw;
  const int Brow = wc * 64 + frow;

  const int subrow = tid >> 3;               // 0..63
  const int chunk = tid & 7;
  const int scb = (chunk << 4) ^ ((subrow & 7) << 4);  // pre-swizzled src col
  const char* GfB = (const char*)Gf;
  char* BbB = (char*)&Bbuf[0][0];

  // per-thread A base: row r0 + wr*128 + frow, k-byte fgrp*16 (no swizzle --
  // registers, not LDS). Frag (m,ks,kt) at +m*32768 + kt*128 + ks*64.
  const char* Aptr = (const char*)Hf + (size_t)(r0 + wr * 128 + frow) * 2048 + fgrp * 16;

  f32x4 acc[8][4];
  #pragma unroll
  for (int m = 0; m < 8; ++m)
    #pragma unroll
    for (int n = 0; n < 4; ++n) acc[m][n] = (f32x4){0.f, 0.f, 0.f, 0.f};

  // stage one B half-unit u (cols n01 (u=0) / n23 (u=1) of all 4 wc strips), 2 loads
  auto stBh = [&](char* dst, int kt, int u) {
    {
      const int rb = subrow;
      const int cr = ((rb >> 5) << 6) + (rb & 31) + (u << 5);
      gload_lds16(GfB + (size_t)(n0g + cr) * 2048 + (size_t)kt * 128 + scb,
                  dst + cr * 128 + (chunk << 4));
    }
    {
      const int rb = 64 + subrow;
      const int cr = ((rb >> 5) << 6) + (rb & 31) + (u << 5);
      gload_lds16(GfB + (size_t)(n0g + cr) * 2048 + (size_t)kt * 128 + scb,
                  dst + cr * 128 + (chunk << 4));
    }
  };

  f16x8 AP[8][2], AQ[8][2], b[4][2];

  auto loadA = [&](f16x8 (&Ad)[8][2], int kt) {
    #pragma unroll
    for (int m = 0; m < 8; ++m)
      #pragma unroll
      for (int ks = 0; ks < 2; ++ks)
        Ad[m][ks] = *(const f16x8*)(Aptr + m * 32768 + kt * 128 + ks * 64);
  };

  auto TILE = [&](f16x8 (&Acur)[8][2], f16x8 (&Anext)[8][2], int cs, int t, bool doNext) {
    // B(t) staged at top of tile t-1; only the 16 A(t) loads are younger ->
    // vmcnt(16) guarantees B-stage retired. Barrier: all waves' stages visible,
    // and all waves' tile t-1 LDS reads are long complete (consumed by MFMAs).
    VMCNT(16);
    __builtin_amdgcn_s_barrier();
    const char* Bc = BbB + cs * 32768;
    char* Bn = BbB + (cs ^ 1) * 32768;
    #pragma unroll
    for (int n = 0; n < 4; ++n) {
      b[n][0] = *(const f16x8*)(Bc + (Brow + n * 16) * 128 + cb0);
      b[n][1] = *(const f16x8*)(Bc + (Brow + n * 16) * 128 + cb1);
    }
    if (doNext) {
      stBh(Bn, t + 1, 0);
      stBh(Bn, t + 1, 1);
      loadA(Anext, t + 1);
    }
    __builtin_amdgcn_sched_barrier(0);
    __builtin_amdgcn_s_setprio(1);
    #pragma unroll
    for (int n = 0; n < 4; ++n)
      #pragma unroll
      for (int ks = 0; ks < 2; ++ks)
        #pragma unroll
        for (int m = 0; m < 8; ++m)
          acc[m][n] = __builtin_amdgcn_mfma_f32_16x16x32_f16(Acur[m][ks], b[n][ks], acc[m][n], 0, 0, 0);
    __builtin_amdgcn_s_setprio(0);
    __builtin_amdgcn_sched_barrier(0);
  };

  // prologue: stage B(0) into slot 0, load A(0) into AP
  stBh(BbB, 0, 0);
  stBh(BbB, 0, 1);
  loadA(AP, 0);

  #pragma unroll 1
  for (int it = 0; it < 8; ++it) {
    TILE(AP, AQ, 0, 2 * it, true);
    TILE(AQ, AP, 1, 2 * it + 1, it < 7);
  }

  // epilogue: rowwise dot with shifted h (f16->f32), reduce over 16 lanes
  #pragma unroll
  for (int m = 0; m < 8; ++m) {
    #pragma unroll
    for (int reg = 0; reg < 4; ++reg) {
      const int rl = wr * 128 + m * 16 + fgrp * 4 + reg;
      const int gr = r0 + rl;
      float sum = 0.f;
      if (((gr + 1) & (S - 1)) != 0) {
        const u16* hrow = Hf + (size_t)(gr + 1) * D + n0g + wc * 64 + frow;
        #pragma unroll
        for (int n = 0; n < 4; ++n)
          sum = fmaf(acc[m][n][reg], h2f(hrow[n * 16]), sum);
      }
      #pragma unroll
      for (int off = 1; off < 16; off <<= 1) sum += __shfl_xor(sum, off, 64);
      if (frow == 0) adjp[wc][rl] = sum;
    }
  }
  __syncthreads();
  if (tid < 256) {
    adj_part[(size_t)nt * BS + r0 + tid] =
        adjp[0][tid] + adjp[1][tid] + adjp[2][tid] + adjp[3][tid];
  }
}

// ---------------------------------------------------------------- score_flag
__global__ void score_flag(const float* __restrict__ adj_part,
                           const float* __restrict__ sig_temp, const float* __restrict__ sig_thr,
                           const float* __restrict__ noise_u,
                           unsigned char* __restrict__ hard, int* __restrict__ flags,
                           int* __restrict__ fcnt) {
  const int idx = blockIdx.x * 256 + threadIdx.x;
  const int s = idx & (S - 1);
  float sc = 0.f;
  if (s > 0) {
    float a = 0.f;
    #pragma unroll
    for (int p = 0; p < 4; ++p) a += adj_part[(size_t)p * BS + idx - 1];
    sc = a * SCALE;
  }
  const float temp = sig_temp[0], thr = sig_thr[0];
  float pr = 1.f / (1.f + expf(-(sc - thr) / temp));
  pr = fminf(fmaxf(pr, 0.f), 1.f);
  if (s == 0) pr = 1.f;
  const float p = fminf(fmaxf(pr, FEPS), 1.f - FEPS);
  const float lgt = logf(p) - log1pf(-p);
  const float uu = fminf(fmaxf(noise_u[idx], FEPS), 1.f - FEPS);
  const float lgs = logf(uu) - log1pf(-uu);
  const float z = lgt + lgs;
  hard[idx] = (z > 0.f) ? 1 : 0;
  if (s > 0 && fabsf(z) < 1e-3f) {
    const int k = atomicAdd(fcnt, 1);
    if (k < MAXF) flags[k] = idx;
  }
}

// ---------------------------------------------------------------- fixup_part
__global__ __launch_bounds__(256) void fixup_part(const int* __restrict__ flags,
    const int* __restrict__ fcnt, const float* __restrict__ hidden,
    const float* __restrict__ pos, const float* __restrict__ Gf32,
    float* __restrict__ pz) {
  __shared__ float h0s[1024];
  __shared__ float h1s[1024];
  __shared__ float red[4];
  const int t = threadIdx.x;
  const int slice = blockIdx.x & 7;
  const int nf = min(*fcnt, MAXF);
  for (int w = blockIdx.x >> 3; w < nf; w += 32) {
    const int idx = flags[w];
    #pragma unroll
    for (int rr = 0; rr < 2; ++rr) {
      const int r = idx - 1 + rr;
      float* hs = rr ? h1s : h0s;
      const float4 hv = ((const float4*)(hidden + (size_t)r * D))[t];
      const float4 pv = ((const float4*)(pos + (size_t)(r & (S - 1)) * D))[t];
      const float x0 = hv.x + pv.x, x1 = hv.y + pv.y, x2 = hv.z + pv.z, x3 = hv.w + pv.w;
      float ss = x0 * x0 + x1 * x1 + x2 * x2 + x3 * x3;
      #pragma unroll
      for (int m = 1; m < 64; m <<= 1) ss += __shfl_xor(ss, m, 64);
      __syncthreads();
      if ((t & 63) == 0) red[t >> 6] = ss;
      __syncthreads();
      const float nrm = fmaxf(sqrtf(red[0] + red[1] + red[2] + red[3]), 1e-12f);
      hs[4 * t + 0] = x0 / nrm; hs[4 * t + 1] = x1 / nrm;
      hs[4 * t + 2] = x2 / nrm; hs[4 * t + 3] = x3 / nrm;
    }
    __syncthreads();
    const float4 h0v = *(const float4*)&h0s[t << 2];
    float acc = 0.f;
    const int i0 = slice << 7;
    #pragma unroll 4
    for (int i = i0; i < i0 + 128; ++i) {
      const float4 g = ((const float4*)(Gf32 + (size_t)i * D))[t];
      const float d = g.x * h0v.x + g.y * h0v.y + g.z * h0v.z + g.w * h0v.w;
      acc = fmaf(h1s[i], d, acc);
    }
    #pragma unroll
    for (int m = 1; m < 64; m <<= 1) acc += __shfl_xor(acc, m, 64);
    __syncthreads();
    if ((t & 63) == 0) red[t >> 6] = acc;
    __syncthreads();
    if (t == 0) pz[(size_t)w * 8 + slice] = red[0] + red[1] + red[2] + red[3];
    __syncthreads();
  }
}

// ---------------------------------------------------------------- fixup_final
__global__ void fixup_final(const int* __restrict__ flags, const int* __restrict__ fcnt,
    const float* __restrict__ pz,
    const float* __restrict__ sig_temp, const float* __restrict__ sig_thr,
    const float* __restrict__ noise_u, unsigned char* __restrict__ hard) {
  const int w = blockIdx.x * 256 + threadIdx.x;
  const int nf = min(*fcnt, MAXF);
  if (w >= nf) return;
  const int idx = flags[w];
  float a = 0.f;
  #pragma unroll
  for (int p = 0; p < 8; ++p) a += pz[(size_t)w * 8 + p];
  const float sc = a * SCALE;
  const float temp = sig_temp[0], thr = sig_thr[0];
  float pr = 1.f / (1.f + expf(-(sc - thr) / temp));
  pr = fminf(fmaxf(pr, 0.f), 1.f);
  const float p = fminf(fmaxf(pr, FEPS), 1.f - FEPS);
  const float lgt = logf(p) - log1pf(-p);
  const float uu = fminf(fmaxf(noise_u[idx], FEPS), 1.f - FEPS);
  const float lgs = logf(uu) - log1pf(-uu);
  hard[idx] = ((lgt + lgs) > 0.f) ? 1 : 0;
}

// ---------------------------------------------------------------- decide_scan
__global__ void decide_scan(const unsigned char* __restrict__ hard_,
                            int* __restrict__ seg_start, int* __restrict__ nseg_out,
                            float* __restrict__ kf_out) {
  const int b = blockIdx.x, t = threadIdx.x;
  __shared__ int ssum[256];
  const uint4 hv = ((const uint4*)(hard_ + (size_t)b * S))[t];
  const uint32_t wds[4] = {hv.x, hv.y, hv.z, hv.w};
  const uint32_t bsum = hv.x + hv.y + hv.z + hv.w;
  const int loc = (int)((bsum & 255) + ((bsum >> 8) & 255) +
                        ((bsum >> 16) & 255) + (bsum >> 24));
  ssum[t] = loc;
  __syncthreads();
  for (int off = 1; off < 256; off <<= 1) {
    int v = ssum[t];
    if (t >= off) v += ssum[t - off];
    __syncthreads();
    ssum[t] = v;
    __syncthreads();
  }
  const int ktot = ssum[255];
  int cum = ssum[t] - loc;
  #pragma unroll
  for (int e = 0; e < 16; ++e) {
    const int s = (t << 4) + e;
    const int bit = (int)((wds[e >> 2] >> ((e & 3) * 8)) & 1);
    const int pseg = min(max(cum - 1, 0), S - 1);
    cum += bit;
    const int seg = min(max(cum - 1, 0), S - 1);
    if (s == 0 || seg != pseg) seg_start[b * S + seg] = s;
  }
  if (t == 0) {
    nseg_out[b] = min(max(ktot, 1), S);
    kf_out[b] = (float)ktot;
  }
}

// ---------------------------------------------------------------- pool
__global__ void pool(const u16* __restrict__ Hf,
                     const int* __restrict__ seg_start, const int* __restrict__ nseg_arr,
                     float* __restrict__ out) {
  const int j = blockIdx.x, b = blockIdx.y, t = threadIdx.x;
  const int ns = nseg_arr[b];
  float4* o = (float4*)(out + (((size_t)j * Bb + b) << 10));
  if (j >= ns) {
    o[t] = (float4){0.f, 0.f, 0.f, 0.f};
    return;
  }
  const int s0 = seg_start[b * S + j];
  const int s1 = (j + 1 < ns) ? seg_start[b * S + j + 1] : S;
  float a0 = 0.f, a1 = 0.f, a2 = 0.f, a3 = 0.f;
  for (int s = s0; s < s1; ++s) {
    const ushort4 hv = *(const ushort4*)(Hf + (((size_t)b * S + s) << 10) + (t << 2));
    a0 += h2f(hv.x); a1 += h2f(hv.y); a2 += h2f(hv.z); a3 += h2f(hv.w);
  }
  const float c = (float)(s1 - s0);
  o[t] = (float4){a0 / c, a1 / c, a2 / c, a3 / c};
}

// ---------------------------------------------------------------- loss
__global__ void loss_k(const float* __restrict__ kf, float* __restrict__ out) {
  const int t = threadIdx.x;
  float lp = 0.f;
  if (t < 8) {
    const float n = 4096.f;
    const float k = kf[t];
    lp = lgammaf(n + 1.f) - lgammaf(k + 1.f) - lgammaf(n - k + 1.f)
       + k * logf(0.2f) + (n - k) * log1pf(-0.2f);
  }
  #pragma unroll
  for (int off = 1; off < 8; off <<= 1) lp += __shfl_xor(lp, off, 64);
  if (t == 0) out[(size_t)BS * 1024] = -(lp / 8.f) / 4096.f;
}

}  // namespace

extern "C" void kernel_launch(void* const* d_in, const int* in_sizes, int n_in,
                              void* d_out, int out_size, void* d_ws, size_t ws_size,
                              hipStream_t stream) {
  (void)in_sizes; (void)n_in; (void)out_size; (void)ws_size;
  const float* hidden = (const float*)d_in[0];
  const float* pos    = (const float*)d_in[1];
  const float* Wq     = (const float*)d_in[2];
  const float* Wk     = (const float*)d_in[3];
  const float* stemp  = (const float*)d_in[4];
  const float* sthr   = (const float*)d_in[5];
  const float* nois   = (const float*)d_in[6];
  float* out = (float*)d_out;
  char* ws = (char*)d_ws;

  // workspace layout (bytes)
  u16*   Hf        = (u16*)(ws);                       // 67,108,864 (f16 bits)
  u16*   Gf16      = (u16*)(ws + 67108864);            //  2,097,152
  float* Gf32      = (float*)(ws + 69206016);          //  4,194,304
  float* adj_part  = (float*)(ws + 73400320);          //  1,048,576 (4 x BS f32 used)
  unsigned char* hard = (unsigned char*)(ws + 74448896); //   32,768
  int*   flags     = (int*)(ws + 74481664);            //     16,384 (MAXF ints)
  float* pz        = (float*)(ws + 74498048);          //    131,072 (MAXF x 8 f32)
  int*   fcnt      = (int*)(ws + 74629120);            //         64
  int*   seg_start = (int*)(ws + 74629184);            //    131,072
  int*   nseg      = (int*)(ws + 74760256);            //         64
  float* kf        = (float*)(ws + 74760320);          //         64
  float* Gpart     = (float*)(ws + 74760384);          // 16,777,216 (4 x 1024^2 f32)

  hipLaunchKernelGGL(prep_h,      dim3(BS),         dim3(256), 0, stream, hidden, pos, Hf, fcnt);
  hipLaunchKernelGGL(gemm_G_part, dim3(16, 16, 4),  dim3(256), 0, stream, Wq, Wk, Gpart);
  hipLaunchKernelGGL(gemm_G_comb, dim3(1024),       dim3(256), 0, stream, Gpart, Gf32, Gf16);
  hipLaunchKernelGGL(gemm_main,   dim3(512),        dim3(512), 0, stream, Hf, Gf16, adj_part);
  hipLaunchKernelGGL(score_flag,  dim3(BS/256),     dim3(256), 0, stream, adj_part, stemp, sthr, nois, hard, flags, fcnt);
  hipLaunchKernelGGL(fixup_part,  dim3(256),        dim3(256), 0, stream, flags, fcnt, hidden, pos, Gf32, pz);
  hipLaunchKernelGGL(fixup_final, dim3(MAXF/256),   dim3(256), 0, stream, flags, fcnt, pz, stemp, sthr, nois, hard);
  hipLaunchKernelGGL(decide_scan, dim3(Bb),         dim3(256), 0, stream, hard, seg_start, nseg, kf);
  hipLaunchKernelGGL(pool,        dim3(S, Bb),      dim3(256), 0, stream, Hf, seg_start, nseg, out);
  hipLaunchKernelGGL(loss_k,      dim3(1),          dim3(64),  0, stream, kf, out);
}

// Round 8
// 300.897 us; speedup vs baseline: 5.7829x; 5.7829x over previous
//
#include <hip/hip_runtime.h>
#include <stdint.h>

namespace {

constexpr int Bb = 8, S = 4096, D = 1024, BS = 32768;
constexpr float SCALE = 0.08838834764831845f;           // (D/NUM_HEADS)^-0.5
constexpr float FEPS  = 1.1920928955078125e-07f;        // float32 eps (2^-23)
constexpr int MAXF = 4096;                              // max rescued items

typedef unsigned short u16;
typedef __attribute__((ext_vector_type(8))) _Float16 f16x8;
typedef __attribute__((ext_vector_type(4))) float    f32x4;

__device__ __forceinline__ u16 f2h(float f) {
  _Float16 h = (_Float16)f;
  return __builtin_bit_cast(u16, h);
}
__device__ __forceinline__ float h2f(u16 u) {
  return (float)__builtin_bit_cast(_Float16, u);
}
__device__ __forceinline__ void gload_lds16(const void* g, void* l) {
  __builtin_amdgcn_global_load_lds((const __attribute__((address_space(1))) void*)g,
                                   (__attribute__((address_space(3))) void*)l, 16, 0, 0);
}
#define VMCNT(n) asm volatile("s_waitcnt vmcnt(" #n ")" ::: "memory")

// ---------------------------------------------------------------- prep_h
__global__ void prep_h(const float* __restrict__ hidden, const float* __restrict__ pos,
                       u16* __restrict__ Hf, int* __restrict__ fcnt) {
  if (blockIdx.x == 0 && threadIdx.x == 0) *fcnt = 0;
  const int r = blockIdx.x;
  const int t = threadIdx.x;
  const float4 hv = ((const float4*)(hidden + (size_t)r * D))[t];
  const float4 pv = ((const float4*)(pos + (size_t)(r & (S - 1)) * D))[t];
  float x0 = hv.x + pv.x, x1 = hv.y + pv.y, x2 = hv.z + pv.z, x3 = hv.w + pv.w;
  float ss = x0 * x0 + x1 * x1 + x2 * x2 + x3 * x3;
  #pragma unroll
  for (int m = 1; m < 64; m <<= 1) ss += __shfl_xor(ss, m, 64);
  __shared__ float red[4];
  if ((t & 63) == 0) red[t >> 6] = ss;
  __syncthreads();
  const float nrm = fmaxf(sqrtf(red[0] + red[1] + red[2] + red[3]), 1e-12f);
  ((ushort4*)(Hf + (size_t)r * D))[t] = make_ushort4(
      f2h(x0 / nrm), f2h(x1 / nrm), f2h(x2 / nrm), f2h(x3 / nrm));
}

// ---------------------------------------------------------------- gemm_G_part
__global__ void gemm_G_part(const float* __restrict__ Wq, const float* __restrict__ Wk,
                            float* __restrict__ Gpart) {
  __shared__ float Qs[32][64];
  __shared__ float Ks[32][64];
  const int t = threadIdx.x;
  const int i0 = blockIdx.x * 64, j0 = blockIdx.y * 64;
  const int kz = blockIdx.z * 256;
  const int tx = t & 15, ty = t >> 4;
  float acc[4][4] = {};
  for (int k0 = kz; k0 < kz + 256; k0 += 32) {
    #pragma unroll
    for (int q = 0; q < 2; ++q) {
      const int c = t + q * 256;
      const int row = c >> 4, c4 = (c & 15) << 2;
      *(float4*)&Qs[row][c4] = *(const float4*)&Wq[(size_t)(k0 + row) * D + i0 + c4];
      *(float4*)&Ks[row][c4] = *(const float4*)&Wk[(size_t)(k0 + row) * D + j0 + c4];
    }
    __syncthreads();
    #pragma unroll 8
    for (int kk = 0; kk < 32; ++kk) {
      const float4 qa = *(const float4*)&Qs[kk][tx << 2];
      const float4 kb = *(const float4*)&Ks[kk][ty << 2];
      const float qq[4] = {qa.x, qa.y, qa.z, qa.w};
      const float kv[4] = {kb.x, kb.y, kb.z, kb.w};
      #pragma unroll
      for (int a = 0; a < 4; ++a)
        #pragma unroll
        for (int bj = 0; bj < 4; ++bj) acc[a][bj] = fmaf(qq[a], kv[bj], acc[a][bj]);
    }
    __syncthreads();
  }
  float* gp = Gpart + (size_t)blockIdx.z * 1048576;
  #pragma unroll
  for (int a = 0; a < 4; ++a) {
    const int i = i0 + (tx << 2) + a;
    *(float4*)&gp[(size_t)i * D + j0 + (ty << 2)] =
        make_float4(acc[a][0], acc[a][1], acc[a][2], acc[a][3]);
  }
}

// ---------------------------------------------------------------- gemm_G_comb
__global__ void gemm_G_comb(const float* __restrict__ Gpart,
                            float* __restrict__ Gf32, u16* __restrict__ Gf16) {
  const size_t e = ((size_t)blockIdx.x * 256 + threadIdx.x) * 4;
  float4 a = *(const float4*)&Gpart[e];
  #pragma unroll
  for (int z = 1; z < 4; ++z) {
    const float4 p = *(const float4*)&Gpart[(size_t)z * 1048576 + e];
    a.x += p.x; a.y += p.y; a.z += p.z; a.w += p.w;
  }
  *(float4*)&Gf32[e] = a;
  *(ushort4*)&Gf16[e] = make_ushort4(f2h(a.x), f2h(a.y), f2h(a.z), f2h(a.w));
}

// ---------------------------------------------------------------- gemm_main
// fp16 MFMA GEMM: A global->register (two 8-frag half-tile banks, compiler
// counted-vmcnt), B via LDS double-buffer (swizzled, 0-conflict), one barrier
// + VMCNT(8) per tile. BM=BN=256 BK=64, 8 waves (2 wr x 4 wc), per-wave
// 128x64. launch_bounds(512,2): 256-reg cap; ~105 VGPR + 128 AGPR fits (R7's
// (512,4)=128-cap caused the full-scratch spill disaster).
// Per tile: {VMCNT(8); bar; b-ks0 reads; load A1<-ks1(t); stage B(t+1);
// MFMA ks0; b-ks1 reads; load A0<-ks0(t+1); MFMA ks1}. Younger-than-stage
// is always exactly the 8 A0 loads -> VMCNT(8) proves B(t) landed; compiler
// emits counted vmcnt(12) for A banks (never drains the pipe).
// Fused epilogue: adj_part[nt][r] = sum_{i in tile} U[r,i]*Hf[r+1,i].
__global__ __launch_bounds__(512, 2) void gemm_main(
    const u16* __restrict__ Hf, const u16* __restrict__ Gf,
    float* __restrict__ adj_part) {
  __shared__ u16 Bbuf[2][16384];      // 2 x 32KB (256 rows x 64 k)
  __shared__ float adjp[4][256];

  const int tid = threadIdx.x;
  const int bid = blockIdx.x;
  const int swz = (bid & 7) * 64 + (bid >> 3);   // XCD swizzle (512 % 8 == 0)
  const int mt = swz >> 2, nt = swz & 3;
  const int r0 = mt << 8;
  const int n0g = nt << 8;

  const int wave = tid >> 6, lane = tid & 63;
  const int wr = wave >> 2;           // 0..1 -> rows wr*128
  const int wc = wave & 3;            // 0..3 -> cols wc*64
  const int frow = lane & 15;
  const int fgrp = lane >> 4;
  const int sw = (lane & 7) << 4;
  const int cb0 = (fgrp * 16) ^ sw;
  const int cb1 = (64 + fgrp * 16) ^ sw;
  const int Brow = wc * 64 + frow;

  const int subrow = tid >> 3;               // 0..63
  const int chunk = tid & 7;
  const int scb = (chunk << 4) ^ ((subrow & 7) << 4);  // pre-swizzled src col
  const char* GfB = (const char*)Gf;
  char* BbB = (char*)&Bbuf[0][0];

  // per-thread A base: row r0 + wr*128 + frow; frag (m,kt,ks) at
  // +m*32768 + kt*128 + ks*64 + fgrp*16 (registers -- no swizzle needed).
  const char* Aptr = (const char*)Hf + (size_t)(r0 + wr * 128 + frow) * 2048 + fgrp * 16;

  f32x4 acc[8][4];
  #pragma unroll
  for (int m = 0; m < 8; ++m)
    #pragma unroll
    for (int n = 0; n < 4; ++n) acc[m][n] = (f32x4){0.f, 0.f, 0.f, 0.f};

  // stage one B half-unit u (cols n01 (u=0) / n23 (u=1) of all 4 wc strips), 2 loads
  auto stBh = [&](char* dst, int kt, int u) {
    {
      const int rb = subrow;
      const int cr = ((rb >> 5) << 6) + (rb & 31) + (u << 5);
      gload_lds16(GfB + (size_t)(n0g + cr) * 2048 + (size_t)kt * 128 + scb,
                  dst + cr * 128 + (chunk << 4));
    }
    {
      const int rb = 64 + subrow;
      const int cr = ((rb >> 5) << 6) + (rb & 31) + (u << 5);
      gload_lds16(GfB + (size_t)(n0g + cr) * 2048 + (size_t)kt * 128 + scb,
                  dst + cr * 128 + (chunk << 4));
    }
  };

  f16x8 A0[8], A1[8];

#define LOADA(BANK, KT, KS) { \
  _Pragma("unroll") \
  for (int m = 0; m < 8; ++m) \
    BANK[m] = *(const f16x8*)(Aptr + m * 32768 + (KT) * 128 + (KS) * 64); }

#define MFMA32(BANK, B0, B1, B2, B3) \
  _Pragma("unroll") \
  for (int m = 0; m < 8; ++m) { \
    acc[m][0] = __builtin_amdgcn_mfma_f32_16x16x32_f16(BANK[m], B0, acc[m][0], 0, 0, 0); \
    acc[m][1] = __builtin_amdgcn_mfma_f32_16x16x32_f16(BANK[m], B1, acc[m][1], 0, 0, 0); \
    acc[m][2] = __builtin_amdgcn_mfma_f32_16x16x32_f16(BANK[m], B2, acc[m][2], 0, 0, 0); \
    acc[m][3] = __builtin_amdgcn_mfma_f32_16x16x32_f16(BANK[m], B3, acc[m][3], 0, 0, 0); \
  }

  // prologue: stage B(0) into slot 0 (4 loads), then A-ks0(0) (8 loads)
  stBh(BbB, 0, 0);
  stBh(BbB, 0, 1);
  LOADA(A0, 0, 0)

  #pragma unroll 1
  for (int t = 0; t < 16; ++t) {
    const int cs = t & 1;
    const char* Bc = BbB + cs * 32768;
    char* Bn = BbB + (cs ^ 1) * 32768;

    VMCNT(8);                          // exactly the 8 A0 loads are younger
    __builtin_amdgcn_s_barrier();      // B(t) visible to all; slot cs^1 free

    // b fragments for ks=0
    f16x8 b0a = *(const f16x8*)(Bc + (Brow +  0) * 128 + cb0);
    f16x8 b1a = *(const f16x8*)(Bc + (Brow + 16) * 128 + cb0);
    f16x8 b2a = *(const f16x8*)(Bc + (Brow + 32) * 128 + cb0);
    f16x8 b3a = *(const f16x8*)(Bc + (Brow + 48) * 128 + cb0);
    LOADA(A1, t, 1)                    // ks1 of this tile (used ~400cyc later)
    if (t < 15) { stBh(Bn, t + 1, 0); stBh(Bn, t + 1, 1); }
    __builtin_amdgcn_sched_barrier(0);
    __builtin_amdgcn_s_setprio(1);
    MFMA32(A0, b0a, b1a, b2a, b3a)
    __builtin_amdgcn_s_setprio(0);

    // b fragments for ks=1
    f16x8 b0b = *(const f16x8*)(Bc + (Brow +  0) * 128 + cb1);
    f16x8 b1b = *(const f16x8*)(Bc + (Brow + 16) * 128 + cb1);
    f16x8 b2b = *(const f16x8*)(Bc + (Brow + 32) * 128 + cb1);
    f16x8 b3b = *(const f16x8*)(Bc + (Brow + 48) * 128 + cb1);
    if (t < 15) LOADA(A0, t + 1, 0)    // ks0 of next tile
    __builtin_amdgcn_sched_barrier(0);
    __builtin_amdgcn_s_setprio(1);
    MFMA32(A1, b0b, b1b, b2b, b3b)
    __builtin_amdgcn_s_setprio(0);
  }
#undef LOADA
#undef MFMA32

  // epilogue: rowwise dot with shifted h (f16->f32), reduce over 16 lanes
  #pragma unroll
  for (int m = 0; m < 8; ++m) {
    #pragma unroll
    for (int reg = 0; reg < 4; ++reg) {
      const int rl = wr * 128 + m * 16 + fgrp * 4 + reg;
      const int gr = r0 + rl;
      float sum = 0.f;
      if (((gr + 1) & (S - 1)) != 0) {
        const u16* hrow = Hf + (size_t)(gr + 1) * D + n0g + wc * 64 + frow;
        #pragma unroll
        for (int n = 0; n < 4; ++n)
          sum = fmaf(acc[m][n][reg], h2f(hrow[n * 16]), sum);
      }
      #pragma unroll
      for (int off = 1; off < 16; off <<= 1) sum += __shfl_xor(sum, off, 64);
      if (frow == 0) adjp[wc][rl] = sum;
    }
  }
  __syncthreads();
  if (tid < 256) {
    adj_part[(size_t)nt * BS + r0 + tid] =
        adjp[0][tid] + adjp[1][tid] + adjp[2][tid] + adjp[3][tid];
  }
}

// ---------------------------------------------------------------- score_flag
__global__ void score_flag(const float* __restrict__ adj_part,
                           const float* __restrict__ sig_temp, const float* __restrict__ sig_thr,
                           const float* __restrict__ noise_u,
                           unsigned char* __restrict__ hard, int* __restrict__ flags,
                           int* __restrict__ fcnt) {
  const int idx = blockIdx.x * 256 + threadIdx.x;
  const int s = idx & (S - 1);
  float sc = 0.f;
  if (s > 0) {
    float a = 0.f;
    #pragma unroll
    for (int p = 0; p < 4; ++p) a += adj_part[(size_t)p * BS + idx - 1];
    sc = a * SCALE;
  }
  const float temp = sig_temp[0], thr = sig_thr[0];
  float pr = 1.f / (1.f + expf(-(sc - thr) / temp));
  pr = fminf(fmaxf(pr, 0.f), 1.f);
  if (s == 0) pr = 1.f;
  const float p = fminf(fmaxf(pr, FEPS), 1.f - FEPS);
  const float lgt = logf(p) - log1pf(-p);
  const float uu = fminf(fmaxf(noise_u[idx], FEPS), 1.f - FEPS);
  const float lgs = logf(uu) - log1pf(-uu);
  const float z = lgt + lgs;
  hard[idx] = (z > 0.f) ? 1 : 0;
  if (s > 0 && fabsf(z) < 1e-3f) {
    const int k = atomicAdd(fcnt, 1);
    if (k < MAXF) flags[k] = idx;
  }
}

// ---------------------------------------------------------------- fixup_part
__global__ __launch_bounds__(256) void fixup_part(const int* __restrict__ flags,
    const int* __restrict__ fcnt, const float* __restrict__ hidden,
    const float* __restrict__ pos, const float* __restrict__ Gf32,
    float* __restrict__ pz) {
  __shared__ float h0s[1024];
  __shared__ float h1s[1024];
  __shared__ float red[4];
  const int t = threadIdx.x;
  const int slice = blockIdx.x & 7;
  const int nf = min(*fcnt, MAXF);
  for (int w = blockIdx.x >> 3; w < nf; w += 32) {
    const int idx = flags[w];
    #pragma unroll
    for (int rr = 0; rr < 2; ++rr) {
      const int r = idx - 1 + rr;
      float* hs = rr ? h1s : h0s;
      const float4 hv = ((const float4*)(hidden + (size_t)r * D))[t];
      const float4 pv = ((const float4*)(pos + (size_t)(r & (S - 1)) * D))[t];
      const float x0 = hv.x + pv.x, x1 = hv.y + pv.y, x2 = hv.z + pv.z, x3 = hv.w + pv.w;
      float ss = x0 * x0 + x1 * x1 + x2 * x2 + x3 * x3;
      #pragma unroll
      for (int m = 1; m < 64; m <<= 1) ss += __shfl_xor(ss, m, 64);
      __syncthreads();
      if ((t & 63) == 0) red[t >> 6] = ss;
      __syncthreads();
      const float nrm = fmaxf(sqrtf(red[0] + red[1] + red[2] + red[3]), 1e-12f);
      hs[4 * t + 0] = x0 / nrm; hs[4 * t + 1] = x1 / nrm;
      hs[4 * t + 2] = x2 / nrm; hs[4 * t + 3] = x3 / nrm;
    }
    __syncthreads();
    const float4 h0v = *(const float4*)&h0s[t << 2];
    float acc = 0.f;
    const int i0 = slice << 7;
    #pragma unroll 4
    for (int i = i0; i < i0 + 128; ++i) {
      const float4 g = ((const float4*)(Gf32 + (size_t)i * D))[t];
      const float d = g.x * h0v.x + g.y * h0v.y + g.z * h0v.z + g.w * h0v.w;
      acc = fmaf(h1s[i], d, acc);
    }
    #pragma unroll
    for (int m = 1; m < 64; m <<= 1) acc += __shfl_xor(acc, m, 64);
    __syncthreads();
    if ((t & 63) == 0) red[t >> 6] = acc;
    __syncthreads();
    if (t == 0) pz[(size_t)w * 8 + slice] = red[0] + red[1] + red[2] + red[3];
    __syncthreads();
  }
}

// ---------------------------------------------------------------- fixup_final
__global__ void fixup_final(const int* __restrict__ flags, const int* __restrict__ fcnt,
    const float* __restrict__ pz,
    const float* __restrict__ sig_temp, const float* __restrict__ sig_thr,
    const float* __restrict__ noise_u, unsigned char* __restrict__ hard) {
  const int w = blockIdx.x * 256 + threadIdx.x;
  const int nf = min(*fcnt, MAXF);
  if (w >= nf) return;
  const int idx = flags[w];
  float a = 0.f;
  #pragma unroll
  for (int p = 0; p < 8; ++p) a += pz[(size_t)w * 8 + p];
  const float sc = a * SCALE;
  const float temp = sig_temp[0], thr = sig_thr[0];
  float pr = 1.f / (1.f + expf(-(sc - thr) / temp));
  pr = fminf(fmaxf(pr, 0.f), 1.f);
  const float p = fminf(fmaxf(pr, FEPS), 1.f - FEPS);
  const float lgt = logf(p) - log1pf(-p);
  const float uu = fminf(fmaxf(noise_u[idx], FEPS), 1.f - FEPS);
  const float lgs = logf(uu) - log1pf(-uu);
  hard[idx] = ((lgt + lgs) > 0.f) ? 1 : 0;
}

// ---------------------------------------------------------------- decide_scan
__global__ void decide_scan(const unsigned char* __restrict__ hard_,
                            int* __restrict__ seg_start, int* __restrict__ nseg_out,
                            float* __restrict__ kf_out) {
  const int b = blockIdx.x, t = threadIdx.x;
  __shared__ int ssum[256];
  const uint4 hv = ((const uint4*)(hard_ + (size_t)b * S))[t];
  const uint32_t wds[4] = {hv.x, hv.y, hv.z, hv.w};
  const uint32_t bsum = hv.x + hv.y + hv.z + hv.w;
  const int loc = (int)((bsum & 255) + ((bsum >> 8) & 255) +
                        ((bsum >> 16) & 255) + (bsum >> 24));
  ssum[t] = loc;
  __syncthreads();
  for (int off = 1; off < 256; off <<= 1) {
    int v = ssum[t];
    if (t >= off) v += ssum[t - off];
    __syncthreads();
    ssum[t] = v;
    __syncthreads();
  }
  const int ktot = ssum[255];
  int cum = ssum[t] - loc;
  #pragma unroll
  for (int e = 0; e < 16; ++e) {
    const int s = (t << 4) + e;
    const int bit = (int)((wds[e >> 2] >> ((e & 3) * 8)) & 1);
    const int pseg = min(max(cum - 1, 0), S - 1);
    cum += bit;
    const int seg = min(max(cum - 1, 0), S - 1);
    if (s == 0 || seg != pseg) seg_start[b * S + seg] = s;
  }
  if (t == 0) {
    nseg_out[b] = min(max(ktot, 1), S);
    kf_out[b] = (float)ktot;
  }
}

// ---------------------------------------------------------------- pool
__global__ void pool(const u16* __restrict__ Hf,
                     const int* __restrict__ seg_start, const int* __restrict__ nseg_arr,
                     float* __restrict__ out) {
  const int j = blockIdx.x, b = blockIdx.y, t = threadIdx.x;
  const int ns = nseg_arr[b];
  float4* o = (float4*)(out + (((size_t)j * Bb + b) << 10));
  if (j >= ns) {
    o[t] = (float4){0.f, 0.f, 0.f, 0.f};
    return;
  }
  const int s0 = seg_start[b * S + j];
  const int s1 = (j + 1 < ns) ? seg_start[b * S + j + 1] : S;
  float a0 = 0.f, a1 = 0.f, a2 = 0.f, a3 = 0.f;
  for (int s = s0; s < s1; ++s) {
    const ushort4 hv = *(const ushort4*)(Hf + (((size_t)b * S + s) << 10) + (t << 2));
    a0 += h2f(hv.x); a1 += h2f(hv.y); a2 += h2f(hv.z); a3 += h2f(hv.w);
  }
  const float c = (float)(s1 - s0);
  o[t] = (float4){a0 / c, a1 / c, a2 / c, a3 / c};
}

// ---------------------------------------------------------------- loss
__global__ void loss_k(const float* __restrict__ kf, float* __restrict__ out) {
  const int t = threadIdx.x;
  float lp = 0.f;
  if (t < 8) {
    const float n = 4096.f;
    const float k = kf[t];
    lp = lgammaf(n + 1.f) - lgammaf(k + 1.f) - lgammaf(n - k + 1.f)
       + k * logf(0.2f) + (n - k) * log1pf(-0.2f);
  }
  #pragma unroll
  for (int off = 1; off < 8; off <<= 1) lp += __shfl_xor(lp, off, 64);
  if (t == 0) out[(size_t)BS * 1024] = -(lp / 8.f) / 4096.f;
}

}  // namespace

extern "C" void kernel_launch(void* const* d_in, const int* in_sizes, int n_in,
                              void* d_out, int out_size, void* d_ws, size_t ws_size,
                              hipStream_t stream) {
  (void)in_sizes; (void)n_in; (void)out_size; (void)ws_size;
  const float* hidden = (const float*)d_in[0];
  const float* pos    = (const float*)d_in[1];
  const float* Wq     = (const float*)d_in[2];
  const float* Wk     = (const float*)d_in[3];
  const float* stemp  = (const float*)d_in[4];
  const float* sthr   = (const float*)d_in[5];
  const float* nois   = (const float*)d_in[6];
  float* out = (float*)d_out;
  char* ws = (char*)d_ws;

  // workspace layout (bytes)
  u16*   Hf        = (u16*)(ws);                       // 67,108,864 (f16 bits)
  u16*   Gf16      = (u16*)(ws + 67108864);            //  2,097,152
  float* Gf32      = (float*)(ws + 69206016);          //  4,194,304
  float* adj_part  = (float*)(ws + 73400320);          //  1,048,576 (4 x BS f32 used)
  unsigned char* hard = (unsigned char*)(ws + 74448896); //   32,768
  int*   flags     = (int*)(ws + 74481664);            //     16,384 (MAXF ints)
  float* pz        = (float*)(ws + 74498048);          //    131,072 (MAXF x 8 f32)
  int*   fcnt      = (int*)(ws + 74629120);            //         64
  int*   seg_start = (int*)(ws + 74629184);            //    131,072
  int*   nseg      = (int*)(ws + 74760256);            //         64
  float* kf        = (float*)(ws + 74760320);          //         64
  float* Gpart     = (float*)(ws + 74760384);          // 16,777,216 (4 x 1024^2 f32)

  hipLaunchKernelGGL(prep_h,      dim3(BS),         dim3(256), 0, stream, hidden, pos, Hf, fcnt);
  hipLaunchKernelGGL(gemm_G_part, dim3(16, 16, 4),  dim3(256), 0, stream, Wq, Wk, Gpart);
  hipLaunchKernelGGL(gemm_G_comb, dim3(1024),       dim3(256), 0, stream, Gpart, Gf32, Gf16);
  hipLaunchKernelGGL(gemm_main,   dim3(512),        dim3(512), 0, stream, Hf, Gf16, adj_part);
  hipLaunchKernelGGL(score_flag,  dim3(BS/256),     dim3(256), 0, stream, adj_part, stemp, sthr, nois, hard, flags, fcnt);
  hipLaunchKernelGGL(fixup_part,  dim3(256),        dim3(256), 0, stream, flags, fcnt, hidden, pos, Gf32, pz);
  hipLaunchKernelGGL(fixup_final, dim3(MAXF/256),   dim3(256), 0, stream, flags, fcnt, pz, stemp, sthr, nois, hard);
  hipLaunchKernelGGL(decide_scan, dim3(Bb),         dim3(256), 0, stream, hard, seg_start, nseg, kf);
  hipLaunchKernelGGL(pool,        dim3(S, Bb),      dim3(256), 0, stream, Hf, seg_start, nseg, out);
  hipLaunchKernelGGL(loss_k,      dim3(1),          dim3(64),  0, stream, kf, out);
}